// Round 7
// baseline (282.806 us; speedup 1.0000x reference)
//
#include <hip/hip_runtime.h>

// MyLSTM: 2-layer LSTM (input=3, hidden=4) + MLP head (4->4 tanh -> 1), B=4096, T=1024.
//
// R15 = R10's dual-group topology + R11's LDS-free body. 8 waves: w0,w1 = A (layer 0,
// groups {0,1}/{2,3}), w2,w3 = B (layer 1, groups {0,1}/{2,3}), w4-7 = C (head, pr=w-4).
// w%4 round-robin -> each SIMD hosts ONE dual-group cell wave + ONE light C wave.
//
// Why this works where R10/R13 failed (model validated over R8-R14):
//  - wall = cell wave's serial step chain (~270-346 cyc, 4 dependent trans); issue is
//    NOT the limit (R9: -20 inst/step -> wall flat).
//  - R10 (2 chains/wave) regressed because its body had per-step ds_reads: the
//    wave-global lgkmcnt counter COUPLED the two chains' waits. R11 made the body
//    pure-register; with no LDS in the body the two chains interleave freely: chain-1's
//    ready VALU ops fill chain-0's trans-stall slots at zero arbitration cost.
//  - R13 (two same-stage waves/SIMD) regressed because identical instruction streams
//    phase-lock under round-robin arbitration; a single wave with two software chains
//    has no arbitration.
//  - R12/R14 (prepass overlap) both regressed ~18us by reintroducing body ds_reads.
//    R15 keeps prepass (ds_reads) strictly BEFORE the body, exactly like R11.
//
// Per-group cell math is byte-identical to R8-R14 (same ops, same association) =>
// absmax must stay exactly 0.001953125. Ring/flag protocol verbatim R11, with dual
// polls/publishes per wave (R10's proven dual-group pattern).

#define T_STEPS 1024
#define BATCH   4096
#define CHUNK   16
#define NCHUNK  (T_STEPS / CHUNK)
#define RDEPTH  4   // ring depth in chunks (power of 2)

__device__ __forceinline__ float fast_exp2(float x) {
#if __has_builtin(__builtin_amdgcn_exp2f)
    return __builtin_amdgcn_exp2f(x);
#else
    return exp2f(x);
#endif
}

__device__ __forceinline__ float fast_rcp(float x) {
#if __has_builtin(__builtin_amdgcn_rcpf)
    return __builtin_amdgcn_rcpf(x);
#else
    return 1.0f / x;
#endif
}

// tanh(x) = 2*sigmoid(2x) - 1 = 2/(1+exp2(-2.885390x)) - 1
__device__ __forceinline__ float fast_tanh(float x) {
    return 2.0f * fast_rcp(1.0f + fast_exp2(-2.88539008f * x)) - 1.0f;
}

template <int CTRL>
__device__ __forceinline__ float dpp_mov(float v) {
    int i = __builtin_bit_cast(int, v);
    i = __builtin_amdgcn_mov_dpp(i, CTRL, 0xF, 0xF, true);
    return __builtin_bit_cast(float, i);
}

#define DPP_QB0         0x00   // quad_perm [0,0,0,0] -> i gate
#define DPP_QB1         0x55   // quad_perm [1,1,1,1] -> f gate
#define DPP_QB2         0xAA   // quad_perm [2,2,2,2] -> g gate
#define DPP_QB3         0xFF   // quad_perm [3,3,3,3] -> o gate
#define DPP_ROR8        0x128  // l^8  -> u^2 (on quad-uniform data)
#define DPP_MIRROR      0x140  // l^15 -> u^3 (on quad-uniform data)
#define DPP_HALF_MIRROR 0x141  // l^7  -> u^1 (on quad-uniform data)
#define DPP_QSWAP2      0x4E   // quad_perm [2,3,0,1] -> u^2 within quad
#define DPP_QSWAP1      0xB1   // quad_perm [1,0,3,2] -> u^1 within quad

__global__ __launch_bounds__(512) void lstm_r15_kernel(
    const float* __restrict__ x,
    const float* __restrict__ W_ih0, const float* __restrict__ W_hh0,
    const float* __restrict__ b_ih0, const float* __restrict__ b_hh0,
    const float* __restrict__ W_ih1, const float* __restrict__ W_hh1,
    const float* __restrict__ b_ih1, const float* __restrict__ b_hh1,
    const float* __restrict__ W1, const float* __restrict__ b1,
    const float* __restrict__ W2, const float* __restrict__ b2,
    float* __restrict__ out)
{
    // x stage: [pair][slot][ch*17 + step] (A-private, self-ordered; +17 pad)
    __shared__ float4 xstage[4][2][68];
    // h0 ring A->B: [pair][slot][step][chain], plain-order h[4] per chain (16 KB)
    __shared__ float4 ring0[4][RDEPTH][CHUNK][4];
    // h1 ring B->C: same layout (16 KB)
    __shared__ float4 ring1[4][RDEPTH][CHUNK][4];
    // monotonic chunk counters (value c+1 = chunk c produced / freed)
    __shared__ int done0[4][RDEPTH];
    __shared__ int free0[4][RDEPTH];
    __shared__ int done1[4][RDEPTH];
    __shared__ int free1[4][RDEPTH];

    const int tid  = threadIdx.x;
    const int wave = tid >> 6;
    const int lane = tid & 63;
    const int idx  = lane & 15;         // lane within 16-lane chain group (also step-slot)
    const int rho  = lane & 3;          // role: 0=i,1=f,2=g,3=o
    const int u    = (lane >> 2) & 3;   // hidden unit
    const int r    = rho * 4 + u;       // gate row in 16-row weight matrices
    const int ch   = lane >> 4;         // chain within group

    // init flags, one barrier total (outside hot loop)
    if (tid < 4 * RDEPTH) {
        done0[tid >> 2][tid & 3] = 0;
        free0[tid >> 2][tid & 3] = 0;
        done1[tid >> 2][tid & 3] = 0;
        free1[tid >> 2][tid & 3] = 0;
    }
    __syncthreads();

    // Per-lane activation constants: role g (rho==2) uses tanh = 2*sigma(2x)-1.
    const float am = (rho == 2) ? -2.88539008f : -1.44269504f;
    const float aa = (rho == 2) ? 2.0f : 1.0f;
    const float ab = (rho == 2) ? -1.0f : 0.0f;

    if (wave < 2) {
        // ============ stage A: layer 0 producer, TWO groups per wave =============
        const int g0 = wave * 2, g1 = g0 + 1;
        const float wx0 = W_ih0[r * 3 + 0];
        const float wx1 = W_ih0[r * 3 + 1];
        const float wx2 = W_ih0[r * 3 + 2];
        const float bias0 = b_ih0[r] + b_hh0[r];
        float wh0[4];
#pragma unroll
        for (int k = 0; k < 4; ++k) wh0[k] = W_hh0[r * 4 + (u ^ k)];   // xor order

        float h0_0 = 0.f, c0_0 = 0.f, h0b_0 = 0.f, h0c_0 = 0.f, h0d_0 = 0.f;
        float h0_1 = 0.f, c0_1 = 0.f, h0b_1 = 0.f, h0c_1 = 0.f, h0d_1 = 0.f;

        const float* xrow0 = x + (size_t)(blockIdx.x * 16 + g0 * 4 + ch) * T_STEPS * 3;
        const float* xrow1 = x + (size_t)(blockIdx.x * 16 + g1 * 4 + ch) * T_STEPS * 3;
        // prime: stage chunk 0 into x-slot 0, load chunk 1 into regs (both groups)
        {
            const float* pa = xrow0 + idx * 3;
            xstage[g0][0][ch * 17 + idx] = make_float4(pa[0], pa[1], pa[2], 0.f);
            const float* pb = xrow1 + idx * 3;
            xstage[g1][0][ch * 17 + idx] = make_float4(pb[0], pb[1], pb[2], 0.f);
        }
        const float* p1a = xrow0 + 48 + idx * 3;
        float qa0 = p1a[0], qa1 = p1a[1], qa2 = p1a[2];
        const float* p1b = xrow1 + 48 + idx * 3;
        float qb0 = p1b[0], qb1 = p1b[1], qb2 = p1b[2];

        volatile int* ff0 = &free0[g0][0];
        volatile int* ff1 = &free0[g1][0];

        for (int c = 0; c < NCHUNK; ++c) {
            const int s = c & (RDEPTH - 1);
            // ring credit: previous occupant of slot s was chunk c-RDEPTH (both groups)
            if (c >= RDEPTH) {
                const int lim = c - RDEPTH + 1;
                while (ff0[s] < lim || ff1[s] < lim) { __builtin_amdgcn_s_sleep(1); }
            }

            // ---- prepass (all ds_reads BEFORE the body): both groups' xg -> regs ----
            const float4* xs0 = &xstage[g0][c & 1][ch * 17];
            const float4* xs1 = &xstage[g1][c & 1][ch * 17];
            float xg0[CHUNK], xg1[CHUNK];
#pragma unroll
            for (int tt = 0; tt < CHUNK; ++tt) {
                float4 xv0 = xs0[tt];
                xg0[tt] = bias0 + wx0 * xv0.x + wx1 * xv0.y + wx2 * xv0.z;
                float4 xv1 = xs1[tt];
                xg1[tt] = bias0 + wx0 * xv1.x + wx1 * xv1.y + wx2 * xv1.z;
            }

            // ---- body: pure-register, two independent chains interleaved ----
            float hsg0[CHUNK], hsg1[CHUNK];
#pragma unroll
            for (int tt = 0; tt < CHUNK; ++tt) {
                float pre_0 = xg0[tt]
                            + wh0[0] * h0_0 + wh0[1] * h0b_0 + wh0[2] * h0c_0 + wh0[3] * h0d_0;
                float pre_1 = xg1[tt]
                            + wh0[0] * h0_1 + wh0[1] * h0b_1 + wh0[2] * h0c_1 + wh0[3] * h0d_1;
                float a_0 = aa * fast_rcp(1.0f + fast_exp2(am * pre_0)) + ab;
                float a_1 = aa * fast_rcp(1.0f + fast_exp2(am * pre_1)) + ab;
                float gi0 = dpp_mov<DPP_QB0>(a_0);
                float gf0 = dpp_mov<DPP_QB1>(a_0);
                float gg0 = dpp_mov<DPP_QB2>(a_0);
                float go0 = dpp_mov<DPP_QB3>(a_0);
                float gi1 = dpp_mov<DPP_QB0>(a_1);
                float gf1 = dpp_mov<DPP_QB1>(a_1);
                float gg1 = dpp_mov<DPP_QB2>(a_1);
                float go1 = dpp_mov<DPP_QB3>(a_1);
                c0_0 = gf0 * c0_0 + gi0 * gg0;
                c0_1 = gf1 * c0_1 + gi1 * gg1;
                h0_0 = go0 * fast_tanh(c0_0);
                h0_1 = go1 * fast_tanh(c0_1);
                h0b_0 = dpp_mov<DPP_HALF_MIRROR>(h0_0);
                h0c_0 = dpp_mov<DPP_ROR8>(h0_0);
                h0d_0 = dpp_mov<DPP_MIRROR>(h0_0);
                h0b_1 = dpp_mov<DPP_HALF_MIRROR>(h0_1);
                h0c_1 = dpp_mov<DPP_ROR8>(h0_1);
                h0d_1 = dpp_mov<DPP_MIRROR>(h0_1);
                hsg0[tt] = h0_0;
                hsg1[tt] = h0_1;
            }

            // ---- batched ring writes (one exec-mask set, 32 stores) ----
            if (rho == 0) {
                float* rw0 = &((float*)&ring0[g0][s][0][ch])[u];   // step stride 16 floats
                float* rw1 = &((float*)&ring0[g1][s][0][ch])[u];
#pragma unroll
                for (int tt = 0; tt < CHUNK; ++tt) {
                    rw0[tt * 16] = hsg0[tt];
                    rw1[tt * 16] = hsg1[tt];
                }
            }
            // publish chunk c (both groups)
            __threadfence_block();
            if (lane == 0) { done0[g0][s] = c + 1; done0[g1][s] = c + 1; }

            // stage chunk c+1 (regs loaded last chunk), prefetch chunk c+2
            if (c < NCHUNK - 1) {
                xstage[g0][(c + 1) & 1][ch * 17 + idx] = make_float4(qa0, qa1, qa2, 0.f);
                xstage[g1][(c + 1) & 1][ch * 17 + idx] = make_float4(qb0, qb1, qb2, 0.f);
            }
            if (c < NCHUNK - 2) {
                const float* pa = xrow0 + (c + 2) * 48 + idx * 3;
                qa0 = pa[0]; qa1 = pa[1]; qa2 = pa[2];
                const float* pb = xrow1 + (c + 2) * 48 + idx * 3;
                qb0 = pb[0]; qb1 = pb[1]; qb2 = pb[2];
            }
        }
    } else if (wave < 4) {
        // ========= stage B: layer 1 (cell only), TWO groups per wave =============
        const int g0 = (wave - 2) * 2, g1 = g0 + 1;
        const float bias1 = b_ih1[r] + b_hh1[r];
        float wi1[4], wh1[4];
#pragma unroll
        for (int k = 0; k < 4; ++k) {
            wi1[k] = W_ih1[r * 4 + k];          // PLAIN order (ring h0 is plain)
            wh1[k] = W_hh1[r * 4 + (u ^ k)];    // xor order (register quad)
        }

        float h1_0 = 0.f, c1_0 = 0.f, h1b_0 = 0.f, h1c_0 = 0.f, h1d_0 = 0.f;
        float h1_1 = 0.f, c1_1 = 0.f, h1b_1 = 0.f, h1c_1 = 0.f, h1d_1 = 0.f;

        volatile int* df0 = &done0[g0][0];
        volatile int* df1 = &done0[g1][0];
        volatile int* f10 = &free1[g0][0];
        volatile int* f11 = &free1[g1][0];

        for (int c = 0; c < NCHUNK; ++c) {
            const int s = c & (RDEPTH - 1);
            while (df0[s] < c + 1 || df1[s] < c + 1) { __builtin_amdgcn_s_sleep(1); }
            if (c >= RDEPTH) {
                const int lim = c - RDEPTH + 1;
                while (f10[s] < lim || f11[s] < lim) { __builtin_amdgcn_s_sleep(1); }
            }
            __threadfence_block();

            // ---- prepass (all ds_reads BEFORE the body): both groups' xb -> regs ----
            const float4* rg0 = &ring0[g0][s][0][ch];   // step stride = 4 float4s
            const float4* rg1 = &ring0[g1][s][0][ch];
            float xb0[CHUNK], xb1[CHUNK];
#pragma unroll
            for (int tt = 0; tt < CHUNK; ++tt) {
                float4 hv0 = rg0[tt * 4];
                xb0[tt] = bias1 + wi1[0] * hv0.x + wi1[1] * hv0.y
                                + wi1[2] * hv0.z + wi1[3] * hv0.w;
                float4 hv1 = rg1[tt * 4];
                xb1[tt] = bias1 + wi1[0] * hv1.x + wi1[1] * hv1.y
                                + wi1[2] * hv1.z + wi1[3] * hv1.w;
            }

            // ---- body: pure-register, two independent chains interleaved ----
            float hsg0[CHUNK], hsg1[CHUNK];
#pragma unroll
            for (int tt = 0; tt < CHUNK; ++tt) {
                float pre_0 = xb0[tt]
                            + wh1[0] * h1_0 + wh1[1] * h1b_0 + wh1[2] * h1c_0 + wh1[3] * h1d_0;
                float pre_1 = xb1[tt]
                            + wh1[0] * h1_1 + wh1[1] * h1b_1 + wh1[2] * h1c_1 + wh1[3] * h1d_1;
                float a_0 = aa * fast_rcp(1.0f + fast_exp2(am * pre_0)) + ab;
                float a_1 = aa * fast_rcp(1.0f + fast_exp2(am * pre_1)) + ab;
                float gi0 = dpp_mov<DPP_QB0>(a_0);
                float gf0 = dpp_mov<DPP_QB1>(a_0);
                float gg0 = dpp_mov<DPP_QB2>(a_0);
                float go0 = dpp_mov<DPP_QB3>(a_0);
                float gi1 = dpp_mov<DPP_QB0>(a_1);
                float gf1 = dpp_mov<DPP_QB1>(a_1);
                float gg1 = dpp_mov<DPP_QB2>(a_1);
                float go1 = dpp_mov<DPP_QB3>(a_1);
                c1_0 = gf0 * c1_0 + gi0 * gg0;
                c1_1 = gf1 * c1_1 + gi1 * gg1;
                h1_0 = go0 * fast_tanh(c1_0);
                h1_1 = go1 * fast_tanh(c1_1);
                h1b_0 = dpp_mov<DPP_HALF_MIRROR>(h1_0);
                h1c_0 = dpp_mov<DPP_ROR8>(h1_0);
                h1d_0 = dpp_mov<DPP_MIRROR>(h1_0);
                h1b_1 = dpp_mov<DPP_HALF_MIRROR>(h1_1);
                h1c_1 = dpp_mov<DPP_ROR8>(h1_1);
                h1d_1 = dpp_mov<DPP_MIRROR>(h1_1);
                hsg0[tt] = h1_0;
                hsg1[tt] = h1_1;
            }

            // ---- batched ring1 writes ----
            if (rho == 0) {
                float* rw0 = &((float*)&ring1[g0][s][0][ch])[u];
                float* rw1 = &((float*)&ring1[g1][s][0][ch])[u];
#pragma unroll
                for (int tt = 0; tt < CHUNK; ++tt) {
                    rw0[tt * 16] = hsg0[tt];
                    rw1[tt * 16] = hsg1[tt];
                }
            }
            // release ring0 slots (prepass reads all consumed; per-wave LDS in-order),
            // then publish ring1 chunks (fence makes data visible before flag)
            if (lane == 0) { free0[g0][s] = c + 1; free0[g1][s] = c + 1; }
            __threadfence_block();
            if (lane == 0) { done1[g0][s] = c + 1; done1[g1][s] = c + 1; }
        }
    } else {
        // =================== stage C: MLP head consumer ==========================
        // Zero-redundancy layout: lane = cch*16 + sb*4 + cu handles (chain cch,
        // step it*4+sb, unit cu) -> 4 timesteps per iteration across 64 lanes.
        const int pr  = wave - 4;           // pair served by this C-wave
        const int cu  = lane & 3;           // hidden unit
        const int sb  = (lane >> 2) & 3;    // step sub-slot
        const int cch = lane >> 4;          // chain within pair
        const int cbatch = blockIdx.x * 16 + pr * 4 + cch;

        float w1r[4];
#pragma unroll
        for (int k = 0; k < 4; ++k) w1r[k] = W1[cu * 4 + k];   // plain order
        const float b1u = b1[cu];
        const float w2u = W2[cu];
        const float b2v = b2[0];
        float* op = out + (size_t)cbatch * T_STEPS;

        volatile int* d1 = &done1[pr][0];

        for (int c = 0; c < NCHUNK; ++c) {
            const int s = c & (RDEPTH - 1);
            while (d1[s] < c + 1) { __builtin_amdgcn_s_sleep(1); }
            __threadfence_block();

            // lane reads h1[chain cch][t = it*4+sb] as one float4 (quad-broadcast,
            // 2-way bank aliasing = free); it*16 float4s = it*256 B imm offset
            const float4* rg = &ring1[pr][s][sb][cch];
            float yq[4];
#pragma unroll
            for (int it = 0; it < 4; ++it) {
                float4 h = rg[it * 16];
                float zp = b1u + w1r[0] * h.x + w1r[1] * h.y
                               + w1r[2] * h.z + w1r[3] * h.w;
                float z  = fast_tanh(zp);
                float yv = w2u * z;
                // sum over the 4 units of the quad: (u + u^2) + (u^1 + u^3) + b2
                float t1 = yv + dpp_mov<DPP_QSWAP2>(yv);
                yq[it]   = t1 + dpp_mov<DPP_QSWAP1>(t1) + b2v;
            }
            // release ring1 slot (all reads consumed above; values live in yq regs)
            if (lane == 0) free1[pr][s] = c + 1;

            // store: 16 active lanes (cch, sb), 4 consecutive floats per chain per it
            if (cu == 0) {
#pragma unroll
                for (int it = 0; it < 4; ++it)
                    op[c * CHUNK + it * 4 + sb] = yq[it];
            }
        }
    }
}

extern "C" void kernel_launch(void* const* d_in, const int* in_sizes, int n_in,
                              void* d_out, int out_size, void* d_ws, size_t ws_size,
                              hipStream_t stream) {
    const float* x     = (const float*)d_in[0];
    const float* W_ih0 = (const float*)d_in[1];
    const float* W_hh0 = (const float*)d_in[2];
    const float* b_ih0 = (const float*)d_in[3];
    const float* b_hh0 = (const float*)d_in[4];
    const float* W_ih1 = (const float*)d_in[5];
    const float* W_hh1 = (const float*)d_in[6];
    const float* b_ih1 = (const float*)d_in[7];
    const float* b_hh1 = (const float*)d_in[8];
    const float* W1    = (const float*)d_in[9];
    const float* b1    = (const float*)d_in[10];
    const float* W2    = (const float*)d_in[11];
    const float* b2    = (const float*)d_in[12];
    float* out = (float*)d_out;

    dim3 grid(BATCH / 16);   // 256 blocks = 1 per CU, 16 chains each
    dim3 block(512);         // 8 waves; w%4 -> S0: A{0,1},C0 | S1: A{2,3},C1
                             //                S2: B{0,1},C2 | S3: B{2,3},C3
    lstm_r15_kernel<<<grid, block, 0, stream>>>(
        x, W_ih0, W_hh0, b_ih0, b_hh0, W_ih1, W_hh1, b_ih1, b_hh1,
        W1, b1, W2, b2, out);
}

// Round 8
// 239.363 us; speedup vs baseline: 1.1815x; 1.1815x over previous
//
#include <hip/hip_runtime.h>

// MyLSTM: 2-layer LSTM (input=3, hidden=4) + MLP head (4->4 tanh -> 1), B=4096, T=1024.
//
// R16 = composition of two PROVEN components, no new mechanisms:
//   - R11's cell structure (best, 147.5 us): LDS-free pure-register step body,
//     per-chunk prepass (all ds_reads BEFORE the body), batched ring writes,
//     credit-ring flags. Stage A is verbatim R11.
//   - R8's head folded back into stage B (proven issue-neutral: R8->R9 head
//     removal changed wall by ZERO cycles) -> stage C and ring1 are DELETED.
//
// Why (model validated over R8-R15): wall = serial dep chain of one cell wave's
// step (346 cyc in R11; ~270-300 pure-latency floor; 4 dependent transcendentals).
// Stall-filling attempts all failed: single-wave 2-chain interleave (R10: 519,
// R15: 474 - in-order issue can't fill trans stalls), same-stage wave pairs
// (R13: 388 - identical streams phase-lock). Mixed-stage A+B pairing is best.
// R16 removes the two remaining above-floor costs with zero math change:
//   1. wave C's arbitration presence on the cell waves' SIMDs (A+B only now);
//   2. B's ring1 writes + done1/free1 flag protocol + h-snapshot array
//      (B now computes y per step - off-chain, rides B's own stall windows,
//      its 2 trans ops self-fill - and stores directly to global).
// 8 waves: w0-3 = A (pr=w), w4-7 = B (pr=w-4); w%4 -> SIMD q hosts A-pr_q + B-pr_q.
//
// Cell math byte-identical to R8-R15; head math byte-identical to R8 => absmax
// must stay exactly 0.001953125. Ring0 protocol verbatim R11: monotonic chunk
// counters, __threadfence_block before done-flag, s_sleep polling.

#define T_STEPS 1024
#define BATCH   4096
#define CHUNK   16
#define NCHUNK  (T_STEPS / CHUNK)
#define RDEPTH  4   // ring depth in chunks (power of 2)

__device__ __forceinline__ float fast_exp2(float x) {
#if __has_builtin(__builtin_amdgcn_exp2f)
    return __builtin_amdgcn_exp2f(x);
#else
    return exp2f(x);
#endif
}

__device__ __forceinline__ float fast_rcp(float x) {
#if __has_builtin(__builtin_amdgcn_rcpf)
    return __builtin_amdgcn_rcpf(x);
#else
    return 1.0f / x;
#endif
}

// tanh(x) = 2*sigmoid(2x) - 1 = 2/(1+exp2(-2.885390x)) - 1
__device__ __forceinline__ float fast_tanh(float x) {
    return 2.0f * fast_rcp(1.0f + fast_exp2(-2.88539008f * x)) - 1.0f;
}

template <int CTRL>
__device__ __forceinline__ float dpp_mov(float v) {
    int i = __builtin_bit_cast(int, v);
    i = __builtin_amdgcn_mov_dpp(i, CTRL, 0xF, 0xF, true);
    return __builtin_bit_cast(float, i);
}

#define DPP_QB0         0x00   // quad_perm [0,0,0,0] -> i gate
#define DPP_QB1         0x55   // quad_perm [1,1,1,1] -> f gate
#define DPP_QB2         0xAA   // quad_perm [2,2,2,2] -> g gate
#define DPP_QB3         0xFF   // quad_perm [3,3,3,3] -> o gate
#define DPP_ROR8        0x128  // l^8  -> u^2 (on quad-uniform data)
#define DPP_MIRROR      0x140  // l^15 -> u^3 (on quad-uniform data)
#define DPP_HALF_MIRROR 0x141  // l^7  -> u^1 (on quad-uniform data)

__global__ __launch_bounds__(512) void lstm_r16_kernel(
    const float* __restrict__ x,
    const float* __restrict__ W_ih0, const float* __restrict__ W_hh0,
    const float* __restrict__ b_ih0, const float* __restrict__ b_hh0,
    const float* __restrict__ W_ih1, const float* __restrict__ W_hh1,
    const float* __restrict__ b_ih1, const float* __restrict__ b_hh1,
    const float* __restrict__ W1, const float* __restrict__ b1,
    const float* __restrict__ W2, const float* __restrict__ b2,
    float* __restrict__ out)
{
    // x stage: [pair][slot][ch*17 + step] (A-private, self-ordered; +17 pad)
    __shared__ float4 xstage[4][2][68];
    // h0 ring A->B: [pair][slot][step][chain], plain-order h[4] per chain (16 KB)
    __shared__ float4 ring0[4][RDEPTH][CHUNK][4];
    // monotonic chunk counters (value c+1 = chunk c produced / freed)
    __shared__ int done0[4][RDEPTH];
    __shared__ int free0[4][RDEPTH];

    const int tid  = threadIdx.x;
    const int wave = tid >> 6;
    const int stg  = wave >> 2;         // 0 = L0 producer, 1 = L1 + head consumer
    const int pr   = wave & 3;          // pair index: A/B waves with same pr share ring
    const int lane = tid & 63;
    const int idx  = lane & 15;         // lane within 16-lane chain group (also step-slot)
    const int rho  = lane & 3;          // role: 0=i,1=f,2=g,3=o
    const int u    = (lane >> 2) & 3;   // hidden unit
    const int r    = rho * 4 + u;       // gate row in 16-row weight matrices
    const int ch   = lane >> 4;         // chain within pair
    const int batch = blockIdx.x * 16 + pr * 4 + ch;

    // init flags, one barrier total (outside hot loop)
    if (tid < 4 * RDEPTH) {
        done0[tid >> 2][tid & 3] = 0;
        free0[tid >> 2][tid & 3] = 0;
    }
    __syncthreads();

    // Per-lane activation constants: role g (rho==2) uses tanh = 2*sigma(2x)-1.
    const float am = (rho == 2) ? -2.88539008f : -1.44269504f;
    const float aa = (rho == 2) ? 2.0f : 1.0f;
    const float ab = (rho == 2) ? -1.0f : 0.0f;

    if (stg == 0) {
        // ======================= stage A: layer 0 producer =======================
        const float wx0 = W_ih0[r * 3 + 0];
        const float wx1 = W_ih0[r * 3 + 1];
        const float wx2 = W_ih0[r * 3 + 2];
        const float bias0 = b_ih0[r] + b_hh0[r];
        float wh0[4];
#pragma unroll
        for (int k = 0; k < 4; ++k) wh0[k] = W_hh0[r * 4 + (u ^ k)];   // xor order

        float h0 = 0.f, c0 = 0.f, h0b = 0.f, h0c = 0.f, h0d = 0.f;

        const float* xrow = x + (size_t)batch * T_STEPS * 3;
        // prime: stage chunk 0 into x-slot 0, load chunk 1 into regs
        const float* p0 = xrow + idx * 3;
        xstage[pr][0][ch * 17 + idx] = make_float4(p0[0], p0[1], p0[2], 0.f);
        const float* p1 = xrow + 48 + idx * 3;
        float q0 = p1[0], q1 = p1[1], q2 = p1[2];

        volatile int* ff = &free0[pr][0];

        for (int c = 0; c < NCHUNK; ++c) {
            const int s = c & (RDEPTH - 1);
            // ring credit: previous occupant of slot s was chunk c-RDEPTH
            if (c >= RDEPTH) {
                while (ff[s] < c - RDEPTH + 1) { __builtin_amdgcn_s_sleep(1); }
            }

            // ---- prepass: x-contribution for all 16 steps -> registers ----
            const float4* xs = &xstage[pr][c & 1][ch * 17];
            float xg[CHUNK];
#pragma unroll
            for (int tt = 0; tt < CHUNK; ++tt) {
                float4 xv = xs[tt];
                xg[tt] = bias0 + wx0 * xv.x + wx1 * xv.y + wx2 * xv.z;
            }

            // ---- body: pure-register recurrence, h snapshots to hs0[] ----
            float hs0[CHUNK];
#pragma unroll
            for (int tt = 0; tt < CHUNK; ++tt) {
                float pre0 = xg[tt]
                           + wh0[0] * h0 + wh0[1] * h0b + wh0[2] * h0c + wh0[3] * h0d;
                float a0 = aa * fast_rcp(1.0f + fast_exp2(am * pre0)) + ab;
                float gi = dpp_mov<DPP_QB0>(a0);
                float gf = dpp_mov<DPP_QB1>(a0);
                float gg = dpp_mov<DPP_QB2>(a0);
                float go = dpp_mov<DPP_QB3>(a0);
                c0 = gf * c0 + gi * gg;
                h0 = go * fast_tanh(c0);
                h0b = dpp_mov<DPP_HALF_MIRROR>(h0);
                h0c = dpp_mov<DPP_ROR8>(h0);
                h0d = dpp_mov<DPP_MIRROR>(h0);
                hs0[tt] = h0;
            }

            // ---- batched ring writes (one exec-mask set, 16 stores) ----
            if (rho == 0) {
                float* rw = &((float*)&ring0[pr][s][0][ch])[u];   // step stride 16 floats
#pragma unroll
                for (int tt = 0; tt < CHUNK; ++tt) rw[tt * 16] = hs0[tt];
            }
            // publish chunk c
            __threadfence_block();
            if (lane == 0) done0[pr][s] = c + 1;

            // stage chunk c+1 (regs loaded last chunk), prefetch chunk c+2
            if (c < NCHUNK - 1)
                xstage[pr][(c + 1) & 1][ch * 17 + idx] = make_float4(q0, q1, q2, 0.f);
            if (c < NCHUNK - 2) {
                const float* p = xrow + (c + 2) * 48 + idx * 3;
                q0 = p[0]; q1 = p[1]; q2 = p[2];
            }
        }
    } else {
        // ============== stage B: layer 1 cell + MLP head (R8 head) ===============
        const float bias1 = b_ih1[r] + b_hh1[r];
        float wi1[4], wh1[4], w1p[4];
#pragma unroll
        for (int k = 0; k < 4; ++k) {
            wi1[k] = W_ih1[r * 4 + k];          // PLAIN order (ring h0 is plain)
            wh1[k] = W_hh1[r * 4 + (u ^ k)];    // xor order (register quad)
            w1p[k] = W1[u * 4 + (u ^ k)];       // xor order (register quad)
        }
        const float b1u = b1[u];
        const float w2u = W2[u];
        const float b2v = b2[0];

        float h1 = 0.f, c1 = 0.f, h1b = 0.f, h1c = 0.f, h1d = 0.f;
        float ysave = 0.f;
        float* op = out + (size_t)batch * T_STEPS;

        volatile int* df = &done0[pr][0];

        for (int c = 0; c < NCHUNK; ++c) {
            const int s = c & (RDEPTH - 1);
            while (df[s] < c + 1) { __builtin_amdgcn_s_sleep(1); }
            __threadfence_block();

            // ---- prepass: ring-h0 contribution for all 16 steps -> registers ----
            const float4* rgp = &ring0[pr][s][0][ch];   // step stride = 4 float4s
            float xb[CHUNK];
#pragma unroll
            for (int tt = 0; tt < CHUNK; ++tt) {
                float4 hv = rgp[tt * 4];
                xb[tt] = bias1 + wi1[0] * hv.x + wi1[1] * hv.y
                               + wi1[2] * hv.z + wi1[3] * hv.w;
            }

            // ---- body: pure-register recurrence + per-step head (off-chain) ----
#pragma unroll
            for (int tt = 0; tt < CHUNK; ++tt) {
                float pre1 = xb[tt]
                           + wh1[0] * h1 + wh1[1] * h1b + wh1[2] * h1c + wh1[3] * h1d;
                float a1 = aa * fast_rcp(1.0f + fast_exp2(am * pre1)) + ab;
                float gi1 = dpp_mov<DPP_QB0>(a1);
                float gf1 = dpp_mov<DPP_QB1>(a1);
                float gg1 = dpp_mov<DPP_QB2>(a1);
                float go1 = dpp_mov<DPP_QB3>(a1);
                c1 = gf1 * c1 + gi1 * gg1;
                h1 = go1 * fast_tanh(c1);
                h1b = dpp_mov<DPP_HALF_MIRROR>(h1);
                h1c = dpp_mov<DPP_ROR8>(h1);
                h1d = dpp_mov<DPP_MIRROR>(h1);

                // head (byte-identical to R8): y = W2 . tanh(W1 h1 + b1) + b2
                float zp = b1u + w1p[0] * h1 + w1p[1] * h1b + w1p[2] * h1c + w1p[3] * h1d;
                float z  = fast_tanh(zp);
                float yv = w2u * z;                              // quad-uniform
                float t1 = yv + dpp_mov<DPP_ROR8>(yv);           // + unit u^2
                float y  = t1 + dpp_mov<DPP_MIRROR>(t1) + b2v;   // + units u^1,u^3

                ysave = (tt == idx) ? y : ysave;
            }
            // release ring0 slot (prepass reads all consumed; per-wave LDS in-order),
            // then store the chunk's outputs (coalesced 16 floats/chain)
            if (lane == 0) free0[pr][s] = c + 1;
            op[c * CHUNK + idx] = ysave;
        }
    }
}

extern "C" void kernel_launch(void* const* d_in, const int* in_sizes, int n_in,
                              void* d_out, int out_size, void* d_ws, size_t ws_size,
                              hipStream_t stream) {
    const float* x     = (const float*)d_in[0];
    const float* W_ih0 = (const float*)d_in[1];
    const float* W_hh0 = (const float*)d_in[2];
    const float* b_ih0 = (const float*)d_in[3];
    const float* b_hh0 = (const float*)d_in[4];
    const float* W_ih1 = (const float*)d_in[5];
    const float* W_hh1 = (const float*)d_in[6];
    const float* b_ih1 = (const float*)d_in[7];
    const float* b_hh1 = (const float*)d_in[8];
    const float* W1    = (const float*)d_in[9];
    const float* b1    = (const float*)d_in[10];
    const float* W2    = (const float*)d_in[11];
    const float* b2    = (const float*)d_in[12];
    float* out = (float*)d_out;

    dim3 grid(BATCH / 16);   // 256 blocks = 1 per CU, 16 chains each
    dim3 block(512);         // 8 waves: 4x A + 4x B; w%4 -> SIMD q: A-pr_q + B-pr_q
    lstm_r16_kernel<<<grid, block, 0, stream>>>(
        x, W_ih0, W_hh0, b_ih0, b_hh0, W_ih1, W_hh1, b_ih1, b_hh1,
        W1, b1, W2, b2, out);
}

// Round 9
// 222.268 us; speedup vs baseline: 1.2724x; 1.0769x over previous
//
#include <hip/hip_runtime.h>

// MyLSTM: 2-layer LSTM (input=3, hidden=4) + MLP head (4->4 tanh -> 1), B=4096, T=1024.
//
// R17 = R11 (147.5 us, best structure: 12 waves, one A+B+C per SIMD, credit rings,
// LDS-free pure-register bodies) + ALGEBRAIC CHAIN-SHORTENING of the cell math.
// First deliberate rounding change of the session (R8-R16 were byte-identical).
//
// Model closed over R8-R16: wall = max(chain ~270-300, issue ~277) + ~70 overlap
// residual; all 5 structural rearrangements failed (R12-R16: 165-202 us); TLP is
// issue-blocked (VALUBusy 80-87%). Only lever left: cut the chain AND issue together.
//
// Four cuts, both cell stages (19 -> 15 chain hops; all cut hops are VALU, 4 trans stay):
//  1. am-fold: weights/bias pre-scaled by -1.4427 (sigmoid rows) / -2.8854 (g row)
//     at init -> pre' feeds exp2 directly (deletes mul).
//  2. scaled-c carry: g-activation emitted as -2.885*tanh via aa=-5.7708, ab=+2.8854
//     (same fma, new constants) -> c' = -2.885*c accumulates scaled, feeds exp2
//     directly (deletes mul). c is never output, so the scale never unwinds.
//  3. tanh epilogue fold: h = (2*go)*rcp - go, go2=go+go off-chain (exact x2)
//     -> deletes fma(2,rcp,-1) and mul(go): -2 hops.
//  4. tree dot: ((xg + w0*h) + w1*hb) + (w2*hc + w3*hd): -1 hop, +1 inst.
// h outputs are UNSCALED (ring h0, ring1 h1, head input all unchanged semantics).
// Stage C (head) verbatim R11. Ring/flag protocol verbatim R11.
//
// absmax: reassociation perturbs trajectories ~1 ulp/step through contractive gates;
// expected ~0.0019-0.0021 (was exactly 0.001953125). Accepted risk - revert if fail.

#define T_STEPS 1024
#define BATCH   4096
#define CHUNK   16
#define NCHUNK  (T_STEPS / CHUNK)
#define RDEPTH  4   // ring depth in chunks (power of 2)

__device__ __forceinline__ float fast_exp2(float x) {
#if __has_builtin(__builtin_amdgcn_exp2f)
    return __builtin_amdgcn_exp2f(x);
#else
    return exp2f(x);
#endif
}

__device__ __forceinline__ float fast_rcp(float x) {
#if __has_builtin(__builtin_amdgcn_rcpf)
    return __builtin_amdgcn_rcpf(x);
#else
    return 1.0f / x;
#endif
}

// tanh(x) = 2*sigmoid(2x) - 1 = 2/(1+exp2(-2.885390x)) - 1   (stage C only)
__device__ __forceinline__ float fast_tanh(float x) {
    return 2.0f * fast_rcp(1.0f + fast_exp2(-2.88539008f * x)) - 1.0f;
}

template <int CTRL>
__device__ __forceinline__ float dpp_mov(float v) {
    int i = __builtin_bit_cast(int, v);
    i = __builtin_amdgcn_mov_dpp(i, CTRL, 0xF, 0xF, true);
    return __builtin_bit_cast(float, i);
}

#define DPP_QB0         0x00   // quad_perm [0,0,0,0] -> i gate
#define DPP_QB1         0x55   // quad_perm [1,1,1,1] -> f gate
#define DPP_QB2         0xAA   // quad_perm [2,2,2,2] -> g gate
#define DPP_QB3         0xFF   // quad_perm [3,3,3,3] -> o gate
#define DPP_ROR8        0x128  // l^8  -> u^2 (on quad-uniform data)
#define DPP_MIRROR      0x140  // l^15 -> u^3 (on quad-uniform data)
#define DPP_HALF_MIRROR 0x141  // l^7  -> u^1 (on quad-uniform data)
#define DPP_QSWAP2      0x4E   // quad_perm [2,3,0,1] -> u^2 within quad
#define DPP_QSWAP1      0xB1   // quad_perm [1,0,3,2] -> u^1 within quad

__global__ __launch_bounds__(768) void lstm_r17_kernel(
    const float* __restrict__ x,
    const float* __restrict__ W_ih0, const float* __restrict__ W_hh0,
    const float* __restrict__ b_ih0, const float* __restrict__ b_hh0,
    const float* __restrict__ W_ih1, const float* __restrict__ W_hh1,
    const float* __restrict__ b_ih1, const float* __restrict__ b_hh1,
    const float* __restrict__ W1, const float* __restrict__ b1,
    const float* __restrict__ W2, const float* __restrict__ b2,
    float* __restrict__ out)
{
    // x stage: [pair][slot][ch*17 + step] (A-private, self-ordered; +17 pad)
    __shared__ float4 xstage[4][2][68];
    // h0 ring A->B: [pair][slot][step][chain], plain-order h[4] per chain (16 KB)
    __shared__ float4 ring0[4][RDEPTH][CHUNK][4];
    // h1 ring B->C: same layout (16 KB)
    __shared__ float4 ring1[4][RDEPTH][CHUNK][4];
    // monotonic chunk counters (value c+1 = chunk c produced / freed)
    __shared__ int done0[4][RDEPTH];
    __shared__ int free0[4][RDEPTH];
    __shared__ int done1[4][RDEPTH];
    __shared__ int free1[4][RDEPTH];

    const int tid  = threadIdx.x;
    const int wave = tid >> 6;
    const int stg  = wave >> 2;         // 0 = L0 producer, 1 = L1 mid, 2 = head consumer
    const int pr   = wave & 3;          // pair index: A/B/C waves with same pr share rings
    const int lane = tid & 63;
    const int idx  = lane & 15;         // lane within 16-lane chain group (also step-slot)
    const int rho  = lane & 3;          // role: 0=i,1=f,2=g,3=o
    const int u    = (lane >> 2) & 3;   // hidden unit
    const int r    = rho * 4 + u;       // gate row in 16-row weight matrices
    const int ch   = lane >> 4;         // chain within pair
    const int batch = blockIdx.x * 16 + pr * 4 + ch;

    // init flags, one barrier total (outside hot loop)
    if (tid < 4 * RDEPTH) {
        done0[tid >> 2][tid & 3] = 0;
        free0[tid >> 2][tid & 3] = 0;
        done1[tid >> 2][tid & 3] = 0;
        free1[tid >> 2][tid & 3] = 0;
    }
    __syncthreads();

    // Per-lane activation constants.
    // amr: row scale folded into weights (g row: tanh arg scale; others: sigmoid).
    // a = aa2*rcp(1+exp2(pre')) + ab2 gives sigmoid for rho!=2 and -2.8854*tanh
    // for rho==2 (pre-scaled gate for the scaled-c carry).
    const float amr = (rho == 2) ? -2.88539008f : -1.44269504f;
    const float aa2 = (rho == 2) ? -5.77078016f : 1.0f;
    const float ab2 = (rho == 2) ?  2.88539008f : 0.0f;

    if (stg == 0) {
        // ======================= stage A: layer 0 producer =======================
        const float wx0 = amr * W_ih0[r * 3 + 0];
        const float wx1 = amr * W_ih0[r * 3 + 1];
        const float wx2 = amr * W_ih0[r * 3 + 2];
        const float bias0 = amr * (b_ih0[r] + b_hh0[r]);
        float wh0[4];
#pragma unroll
        for (int k = 0; k < 4; ++k) wh0[k] = amr * W_hh0[r * 4 + (u ^ k)];  // xor order

        float h0 = 0.f, c0 = 0.f, h0b = 0.f, h0c = 0.f, h0d = 0.f;  // c0 is SCALED carry

        const float* xrow = x + (size_t)batch * T_STEPS * 3;
        // prime: stage chunk 0 into x-slot 0, load chunk 1 into regs
        const float* p0 = xrow + idx * 3;
        xstage[pr][0][ch * 17 + idx] = make_float4(p0[0], p0[1], p0[2], 0.f);
        const float* p1 = xrow + 48 + idx * 3;
        float q0 = p1[0], q1 = p1[1], q2 = p1[2];

        volatile int* ff = &free0[pr][0];

        for (int c = 0; c < NCHUNK; ++c) {
            const int s = c & (RDEPTH - 1);
            // ring credit: previous occupant of slot s was chunk c-RDEPTH
            if (c >= RDEPTH) {
                while (ff[s] < c - RDEPTH + 1) { __builtin_amdgcn_s_sleep(1); }
            }

            // ---- prepass: scaled x-contribution for all 16 steps -> registers ----
            const float4* xs = &xstage[pr][c & 1][ch * 17];
            float xg[CHUNK];
#pragma unroll
            for (int tt = 0; tt < CHUNK; ++tt) {
                float4 xv = xs[tt];
                xg[tt] = bias0 + wx0 * xv.x + wx1 * xv.y + wx2 * xv.z;
            }

            // ---- body: pure-register recurrence (shortened chain) ----
            float hs0[CHUNK];
#pragma unroll
            for (int tt = 0; tt < CHUNK; ++tt) {
                float p01 = (xg[tt] + wh0[0] * h0) + wh0[1] * h0b;   // tree dot
                float p23 = wh0[2] * h0c + wh0[3] * h0d;
                float pre0 = p01 + p23;                              // pre-scaled
                float a0 = aa2 * fast_rcp(1.0f + fast_exp2(pre0)) + ab2;
                float gi = dpp_mov<DPP_QB0>(a0);
                float gf = dpp_mov<DPP_QB1>(a0);
                float gg = dpp_mov<DPP_QB2>(a0);   // = -2.8854*tanh(pre)
                float go = dpp_mov<DPP_QB3>(a0);
                c0 = gf * c0 + gi * gg;            // scaled c carry
                float rr = fast_rcp(1.0f + fast_exp2(c0));
                float go2 = go + go;               // exact x2, off-chain
                h0 = go2 * rr - go;                // = go*tanh(c_true), UNSCALED
                h0b = dpp_mov<DPP_HALF_MIRROR>(h0);
                h0c = dpp_mov<DPP_ROR8>(h0);
                h0d = dpp_mov<DPP_MIRROR>(h0);
                hs0[tt] = h0;
            }

            // ---- batched ring writes (one exec-mask set, 16 stores) ----
            if (rho == 0) {
                float* rw = &((float*)&ring0[pr][s][0][ch])[u];   // step stride 16 floats
#pragma unroll
                for (int tt = 0; tt < CHUNK; ++tt) rw[tt * 16] = hs0[tt];
            }
            // publish chunk c
            __threadfence_block();
            if (lane == 0) done0[pr][s] = c + 1;

            // stage chunk c+1 (regs loaded last chunk), prefetch chunk c+2
            if (c < NCHUNK - 1)
                xstage[pr][(c + 1) & 1][ch * 17 + idx] = make_float4(q0, q1, q2, 0.f);
            if (c < NCHUNK - 2) {
                const float* p = xrow + (c + 2) * 48 + idx * 3;
                q0 = p[0]; q1 = p[1]; q2 = p[2];
            }
        }
    } else if (stg == 1) {
        // ==================== stage B: layer 1 (cell only) =======================
        const float bias1 = amr * (b_ih1[r] + b_hh1[r]);
        float wi1[4], wh1[4];
#pragma unroll
        for (int k = 0; k < 4; ++k) {
            wi1[k] = amr * W_ih1[r * 4 + k];          // PLAIN order (ring h0 is plain)
            wh1[k] = amr * W_hh1[r * 4 + (u ^ k)];    // xor order (register quad)
        }

        float h1 = 0.f, c1 = 0.f, h1b = 0.f, h1c = 0.f, h1d = 0.f;  // c1 SCALED carry

        volatile int* df = &done0[pr][0];
        volatile int* f1 = &free1[pr][0];

        for (int c = 0; c < NCHUNK; ++c) {
            const int s = c & (RDEPTH - 1);
            while (df[s] < c + 1) { __builtin_amdgcn_s_sleep(1); }
            if (c >= RDEPTH) {
                while (f1[s] < c - RDEPTH + 1) { __builtin_amdgcn_s_sleep(1); }
            }
            __threadfence_block();

            // ---- prepass: scaled ring-h0 contribution for all 16 steps ----
            const float4* rgp = &ring0[pr][s][0][ch];   // step stride = 4 float4s
            float xb[CHUNK];
#pragma unroll
            for (int tt = 0; tt < CHUNK; ++tt) {
                float4 hv = rgp[tt * 4];
                xb[tt] = bias1 + wi1[0] * hv.x + wi1[1] * hv.y
                               + wi1[2] * hv.z + wi1[3] * hv.w;
            }

            // ---- body: pure-register recurrence (shortened chain) ----
            float hs1[CHUNK];
#pragma unroll
            for (int tt = 0; tt < CHUNK; ++tt) {
                float p01 = (xb[tt] + wh1[0] * h1) + wh1[1] * h1b;   // tree dot
                float p23 = wh1[2] * h1c + wh1[3] * h1d;
                float pre1 = p01 + p23;                              // pre-scaled
                float a1 = aa2 * fast_rcp(1.0f + fast_exp2(pre1)) + ab2;
                float gi1 = dpp_mov<DPP_QB0>(a1);
                float gf1 = dpp_mov<DPP_QB1>(a1);
                float gg1 = dpp_mov<DPP_QB2>(a1);  // = -2.8854*tanh(pre)
                float go1 = dpp_mov<DPP_QB3>(a1);
                c1 = gf1 * c1 + gi1 * gg1;         // scaled c carry
                float rr = fast_rcp(1.0f + fast_exp2(c1));
                float go2 = go1 + go1;             // exact x2, off-chain
                h1 = go2 * rr - go1;               // UNSCALED h1
                h1b = dpp_mov<DPP_HALF_MIRROR>(h1);
                h1c = dpp_mov<DPP_ROR8>(h1);
                h1d = dpp_mov<DPP_MIRROR>(h1);
                hs1[tt] = h1;
            }

            // ---- batched ring1 writes ----
            if (rho == 0) {
                float* rw = &((float*)&ring1[pr][s][0][ch])[u];
#pragma unroll
                for (int tt = 0; tt < CHUNK; ++tt) rw[tt * 16] = hs1[tt];
            }
            // release ring0 slot (prepass reads all consumed; per-wave LDS in-order),
            // then publish ring1 chunk (fence makes data visible before flag)
            if (lane == 0) free0[pr][s] = c + 1;
            __threadfence_block();
            if (lane == 0) done1[pr][s] = c + 1;
        }
    } else {
        // =================== stage C: MLP head consumer (verbatim R11) ===========
        const int cu  = lane & 3;           // hidden unit
        const int sb  = (lane >> 2) & 3;    // step sub-slot
        const int cch = lane >> 4;          // chain within pair
        const int cbatch = blockIdx.x * 16 + pr * 4 + cch;

        float w1r[4];
#pragma unroll
        for (int k = 0; k < 4; ++k) w1r[k] = W1[cu * 4 + k];   // plain order
        const float b1u = b1[cu];
        const float w2u = W2[cu];
        const float b2v = b2[0];
        float* op = out + (size_t)cbatch * T_STEPS;

        volatile int* d1 = &done1[pr][0];

        for (int c = 0; c < NCHUNK; ++c) {
            const int s = c & (RDEPTH - 1);
            while (d1[s] < c + 1) { __builtin_amdgcn_s_sleep(1); }
            __threadfence_block();

            // lane reads h1[chain cch][t = it*4+sb] as one float4 (quad-broadcast,
            // 2-way bank aliasing = free); it*16 float4s = it*256 B imm offset
            const float4* rg = &ring1[pr][s][sb][cch];
            float yq[4];
#pragma unroll
            for (int it = 0; it < 4; ++it) {
                float4 h = rg[it * 16];
                float zp = b1u + w1r[0] * h.x + w1r[1] * h.y
                               + w1r[2] * h.z + w1r[3] * h.w;
                float z  = fast_tanh(zp);
                float yv = w2u * z;
                // sum over the 4 units of the quad: (u + u^2) + (u^1 + u^3) + b2
                float t1 = yv + dpp_mov<DPP_QSWAP2>(yv);
                yq[it]   = t1 + dpp_mov<DPP_QSWAP1>(t1) + b2v;
            }
            // release ring1 slot (all reads consumed above; values live in yq regs)
            if (lane == 0) free1[pr][s] = c + 1;

            // store: 16 active lanes (cch, sb), 4 consecutive floats per chain per it
            if (cu == 0) {
#pragma unroll
                for (int it = 0; it < 4; ++it)
                    op[c * CHUNK + it * 4 + sb] = yq[it];
            }
        }
    }
}

extern "C" void kernel_launch(void* const* d_in, const int* in_sizes, int n_in,
                              void* d_out, int out_size, void* d_ws, size_t ws_size,
                              hipStream_t stream) {
    const float* x     = (const float*)d_in[0];
    const float* W_ih0 = (const float*)d_in[1];
    const float* W_hh0 = (const float*)d_in[2];
    const float* b_ih0 = (const float*)d_in[3];
    const float* b_hh0 = (const float*)d_in[4];
    const float* W_ih1 = (const float*)d_in[5];
    const float* W_hh1 = (const float*)d_in[6];
    const float* b_ih1 = (const float*)d_in[7];
    const float* b_hh1 = (const float*)d_in[8];
    const float* W1    = (const float*)d_in[9];
    const float* b1    = (const float*)d_in[10];
    const float* W2    = (const float*)d_in[11];
    const float* b2    = (const float*)d_in[12];
    float* out = (float*)d_out;

    dim3 grid(BATCH / 16);   // 256 blocks = 1 per CU, 16 chains each
    dim3 block(768);         // 12 waves: 4x A (L0) + 4x B (L1) + 4x C (head);
                             // w%4 round-robin -> each SIMD gets one A, one B, one C
    lstm_r17_kernel<<<grid, block, 0, stream>>>(
        x, W_ih0, W_hh0, b_ih0, b_hh0, W_ih1, W_hh1, b_ih1, b_hh1,
        W1, b1, W2, b2, out);
}